// Round 1
// baseline (401.149 us; speedup 1.0000x reference)
//
#include <hip/hip_runtime.h>

#define NN 50000
#define NE 400000
#define INF 768
#define HF 16
#define OF 21
#define ELLW 40   // Poisson(8) max-degree guard: P(deg>=40 anywhere) ~ 1e-11

#define FMA4(ACC, SS, VV) { (ACC).x += (SS)*(VV).x; (ACC).y += (SS)*(VV).y; \
                            (ACC).z += (SS)*(VV).z; (ACC).w += (SS)*(VV).w; }

// -----------------------------------------------------------------------------
// ELL build: cnt[d] = in-degree, ell[d*ELLW+i] = src of i-th edge into d.
// -----------------------------------------------------------------------------
__global__ __launch_bounds__(256) void scatter_kernel(const int* __restrict__ src,
                                                      const int* __restrict__ dst,
                                                      int* __restrict__ cnt,
                                                      int* __restrict__ ell) {
    int e = blockIdx.x * 256 + threadIdx.x;
    if (e >= NE) return;
    int d = dst[e];
    int pos = atomicAdd(&cnt[d], 1);
    if (pos < ELLW) ell[d * ELLW + pos] = src[e];
}

// -----------------------------------------------------------------------------
// GEMM1: P = F @ W1  (50000x768 @ 768x16).
// Round-5 lesson: the W1-in-LDS broadcast scheme was LDS-PIPE-bound: 16
// ds_read_b128 per 64 FMAs (~192cy LDS vs 128cy VALU per iter) and the
// row-per-lane F reads hit 64 scattered 16B lines per instr. VALUBusy was
// 8.7%, HBM 14% -> neither pipe near limit, LDS serialization was.
// New scheme: ZERO LDS. Lane (g=lane>>4, ks=(lane>>2)&3, jq=lane&3) owns a
// 4k x 4j W1 fragment in 16 VGPRs, reloaded per 64-k tile straight from
// L1/L2 (48KB W1 stays hot) and REUSED across 8 rows. F reads are wave-
// cooperative: one instr covers one row's contiguous 256B k-tile (4 full
// lines; 4x jq-duplication merges in the coalescer). k-split reduced by
// xor-4/8/16/32 butterfly; lanes 0-3 write 64B/row coalesced. No barriers,
// no LDS -> 6 waves/EU occupancy.
// -----------------------------------------------------------------------------
__global__ __launch_bounds__(256, 6) void gemm1_kernel(const float* __restrict__ F,
                                                       const float* __restrict__ W1,
                                                       float* __restrict__ P) {
    const int tid = threadIdx.x;
    const int wv = tid >> 6, lane = tid & 63;
    const int g = lane >> 4;          // which 16-k subtile of the 64-k tile
    const int u = lane & 15;
    const int ks = u >> 2;            // which 4-k chunk within the subtile
    const int jq = u & 3;             // which 4-j quad of the 16 outputs
    const int koff = g * 16 + ks * 4; // lane's k offset within a 64-k tile
    const int rowbase = blockIdx.x * 32 + wv * 8;

    int roff[8];
#pragma unroll
    for (int r = 0; r < 8; ++r) {
        int row = rowbase + r;
        if (row > NN - 1) row = NN - 1;      // tail clamp: safe read, write masked
        roff[r] = row * INF + koff;
    }

    const float* wbase = W1 + koff * HF + jq * 4;

    float4 acc[8];
#pragma unroll
    for (int r = 0; r < 8; ++r) acc[r] = make_float4(0.f, 0.f, 0.f, 0.f);

    for (int t = 0; t < INF / 64; ++t) {      // 12 k-tiles of 64
        const float* wp = wbase + t * 64 * HF;
        const float4 w0 = *(const float4*)(wp + 0 * HF);
        const float4 w1 = *(const float4*)(wp + 1 * HF);
        const float4 w2 = *(const float4*)(wp + 2 * HF);
        const float4 w3 = *(const float4*)(wp + 3 * HF);
#pragma unroll
        for (int r = 0; r < 8; ++r) {
            const float4 f = *(const float4*)(F + roff[r] + t * 64);
            FMA4(acc[r], f.x, w0);
            FMA4(acc[r], f.y, w1);
            FMA4(acc[r], f.z, w2);
            FMA4(acc[r], f.w, w3);
        }
    }

#pragma unroll
    for (int r = 0; r < 8; ++r) {
        float4 v = acc[r];
#define RED(X) { v.X += __shfl_xor(v.X, 4);  v.X += __shfl_xor(v.X, 8); \
                 v.X += __shfl_xor(v.X, 16); v.X += __shfl_xor(v.X, 32); }
        RED(x) RED(y) RED(z) RED(w)
#undef RED
        const int row = rowbase + r;
        if (lane < 4 && row < NN)
            *(float4*)(P + (size_t)row * HF + jq * 4) = v;
    }
}

// -----------------------------------------------------------------------------
// agg1: A1[n] = sum_{e into n} P[src[e]]. 16 lanes per node: 4 edge-subgroups
// (es) x 4 float4-lanes (q). Butterfly xor 4,8 merges edge groups.
// -----------------------------------------------------------------------------
__global__ __launch_bounds__(256) void agg1_kernel(const float* __restrict__ P,
                                                   const int* __restrict__ cnt,
                                                   const int* __restrict__ ell,
                                                   float* __restrict__ A1) {
    int g = blockIdx.x * 256 + threadIdx.x;
    int node = g >> 4;
    if (node >= NN) return;
    const int l = g & 15, es = l >> 2, q = l & 3;
    int c = cnt[node]; if (c > ELLW) c = ELLW;
    const int* ep = ell + node * ELLW;

    float4 v = {0,0,0,0};
    for (int i = es; i < c; i += 4) {
        int s = ep[i];
        float4 p = *(const float4*)(P + (size_t)s * HF + q * 4);
        v.x += p.x; v.y += p.y; v.z += p.z; v.w += p.w;
    }
#define BFLY2(VAL) { VAL += __shfl_xor(VAL, 4); VAL += __shfl_xor(VAL, 8); }
    BFLY2(v.x) BFLY2(v.y) BFLY2(v.z) BFLY2(v.w)
#undef BFLY2
    if (es == 0)
        *(float4*)(A1 + (size_t)node * HF + q * 4) = v;
}

// -----------------------------------------------------------------------------
// agg2 + output GEMM fused: A2[n] = sum relu(A1[src]+b1) (16 lanes/node),
// then out[n] = A2 @ W2 + b2 via per-q partials + xor 1,2 butterfly.
// -----------------------------------------------------------------------------
__global__ __launch_bounds__(256) void agg2out_kernel(const float* __restrict__ A1,
                                                      const float* __restrict__ b1,
                                                      const int* __restrict__ cnt,
                                                      const int* __restrict__ ell,
                                                      const float* __restrict__ W2,
                                                      const float* __restrict__ b2,
                                                      float* __restrict__ out) {
    __shared__ float W2s[HF * OF];
    __shared__ float b2s[OF];
    const int t = threadIdx.x;
    for (int i = t; i < HF * OF; i += 256) W2s[i] = W2[i];
    if (t < OF) b2s[t] = b2[t];
    __syncthreads();

    int g = blockIdx.x * 256 + t;
    int node = g >> 4;
    if (node >= NN) return;
    const int l = g & 15, es = l >> 2, q = l & 3;

    const float4 bb = *(const float4*)(b1 + q * 4);
    int c = cnt[node]; if (c > ELLW) c = ELLW;
    const int* ep = ell + node * ELLW;

    float4 v = {0,0,0,0};
    for (int i = es; i < c; i += 4) {
        int s = ep[i];
        float4 h = *(const float4*)(A1 + (size_t)s * HF + q * 4);
        h.x = fmaxf(h.x + bb.x, 0.0f);
        h.y = fmaxf(h.y + bb.y, 0.0f);
        h.z = fmaxf(h.z + bb.z, 0.0f);
        h.w = fmaxf(h.w + bb.w, 0.0f);
        v.x += h.x; v.y += h.y; v.z += h.z; v.w += h.w;
    }
#define BFLY2(VAL) { VAL += __shfl_xor(VAL, 4); VAL += __shfl_xor(VAL, 8); }
    BFLY2(v.x) BFLY2(v.y) BFLY2(v.z) BFLY2(v.w)
#undef BFLY2

    const float* w0 = W2s + (q * 4 + 0) * OF;
    const float* w1 = W2s + (q * 4 + 1) * OF;
    const float* w2 = W2s + (q * 4 + 2) * OF;
    const float* w3 = W2s + (q * 4 + 3) * OF;
    float o[OF];
#pragma unroll
    for (int cc = 0; cc < OF; ++cc)
        o[cc] = v.x * w0[cc] + v.y * w1[cc] + v.z * w2[cc] + v.w * w3[cc];
#pragma unroll
    for (int cc = 0; cc < OF; ++cc) {
        o[cc] += __shfl_xor(o[cc], 1);
        o[cc] += __shfl_xor(o[cc], 2);
    }
    if (es == 0) {
        float* op = out + (size_t)node * OF;
        for (int cc = q; cc < OF; cc += 4) op[cc] = o[cc] + b2s[cc];
    }
}

extern "C" void kernel_launch(void* const* d_in, const int* in_sizes, int n_in,
                              void* d_out, int out_size, void* d_ws, size_t ws_size,
                              hipStream_t stream) {
    const float* F   = (const float*)d_in[0];
    const float* W1  = (const float*)d_in[1];
    const float* b1  = (const float*)d_in[2];
    const float* W2  = (const float*)d_in[3];
    const float* b2  = (const float*)d_in[4];
    const int*   src = (const int*)d_in[5];
    const int*   dst = (const int*)d_in[6];
    float* out = (float*)d_out;

    char* ws = (char*)d_ws;
    int*   cnt = (int*)(ws);                       // 200,000 B
    int*   ell = (int*)(ws + 200192);              // 8,000,000 B
    float* P   = (float*)(ws + 8200192);           // 3,200,000 B
    float* A1  = (float*)(ws + 11400192);          // 3,200,000 B

    (void)hipMemsetAsync(cnt, 0, NN * sizeof(int), stream);
    scatter_kernel<<<(NE + 255) / 256, 256, 0, stream>>>(src, dst, cnt, ell);
    gemm1_kernel<<<(NN + 31) / 32, 256, 0, stream>>>(F, W1, P);
    agg1_kernel<<<(NN * 16 + 255) / 256, 256, 0, stream>>>(P, cnt, ell, A1);
    agg2out_kernel<<<(NN * 16 + 255) / 256, 256, 0, stream>>>(A1, b1, cnt, ell, W2, b2, out);
}

// Round 2
// 300.409 us; speedup vs baseline: 1.3353x; 1.3353x over previous
//
#include <hip/hip_runtime.h>

#define NN 50000
#define NE 400000
#define INF 768
#define HF 16
#define OF 21
#define ELLW 40   // Poisson(8) max-degree guard: P(deg>=40 anywhere) ~ 1e-11

#define FMA4(ACC, SS, VV) { (ACC).x += (SS)*(VV).x; (ACC).y += (SS)*(VV).y; \
                            (ACC).z += (SS)*(VV).z; (ACC).w += (SS)*(VV).w; }

// -----------------------------------------------------------------------------
// ELL build: cnt[d] = in-degree, ell[d*ELLW+i] = src of i-th edge into d.
// -----------------------------------------------------------------------------
__global__ __launch_bounds__(256) void scatter_kernel(const int* __restrict__ src,
                                                      const int* __restrict__ dst,
                                                      int* __restrict__ cnt,
                                                      int* __restrict__ ell) {
    int e = blockIdx.x * 256 + threadIdx.x;
    if (e >= NE) return;
    int d = dst[e];
    int pos = atomicAdd(&cnt[d], 1);
    if (pos < ELLW) ell[d * ELLW + pos] = src[e];
}

// -----------------------------------------------------------------------------
// GEMM1: P = F @ W1  (50000x768 @ 768x16).
// Round-6 lesson: round-5's register-tile scheme was SPILLING — VGPR clamped
// to 40 by __launch_bounds__(256,6) while ~68 are live, and the constant-trip
// k-loop got fully unrolled, blowing lifetimes. WRITE_SIZE 6.2->46.9MB (+43.7
// = 400K threads x ~112B scratch) was the tell; VALUBusy fell to 6.5%.
// Fix: launch_bounds(256,3) (budget ~85 VGPRs, 12 waves/CU) + #pragma unroll 1
// on the k-tile loop so only one tile's w0..w3/f are live. Structure kept:
// lane (g,ks,jq) owns a 4k x 4j W1 fragment (16 VGPRs, reloaded per 64-k tile
// from L1-hot W1, reused across 8 rows); F reads are wave-cooperative
// contiguous 256B per instr; xor-4/8/16/32 butterfly; lanes 0-3 write 64B/row.
// Zero LDS, zero barriers, zero bank conflicts.
// -----------------------------------------------------------------------------
__global__ __launch_bounds__(256, 3) void gemm1_kernel(const float* __restrict__ F,
                                                       const float* __restrict__ W1,
                                                       float* __restrict__ P) {
    const int tid = threadIdx.x;
    const int wv = tid >> 6, lane = tid & 63;
    const int g = lane >> 4;          // which 16-k subtile of the 64-k tile
    const int u = lane & 15;
    const int ks = u >> 2;            // which 4-k chunk within the subtile
    const int jq = u & 3;             // which 4-j quad of the 16 outputs
    const int koff = g * 16 + ks * 4; // lane's k offset within a 64-k tile
    const int rowbase = blockIdx.x * 32 + wv * 8;

    int roff[8];
#pragma unroll
    for (int r = 0; r < 8; ++r) {
        int row = rowbase + r;
        if (row > NN - 1) row = NN - 1;      // tail clamp: safe read, write masked
        roff[r] = row * INF + koff;
    }

    const float* wbase = W1 + koff * HF + jq * 4;

    float4 acc[8];
#pragma unroll
    for (int r = 0; r < 8; ++r) acc[r] = make_float4(0.f, 0.f, 0.f, 0.f);

#pragma unroll 1
    for (int t = 0; t < INF / 64; ++t) {      // 12 k-tiles of 64; keep ONE live
        const float* wp = wbase + t * 64 * HF;
        const float4 w0 = *(const float4*)(wp + 0 * HF);
        const float4 w1 = *(const float4*)(wp + 1 * HF);
        const float4 w2 = *(const float4*)(wp + 2 * HF);
        const float4 w3 = *(const float4*)(wp + 3 * HF);
#pragma unroll
        for (int r = 0; r < 8; ++r) {
            const float4 f = *(const float4*)(F + roff[r] + t * 64);
            FMA4(acc[r], f.x, w0);
            FMA4(acc[r], f.y, w1);
            FMA4(acc[r], f.z, w2);
            FMA4(acc[r], f.w, w3);
        }
    }

#pragma unroll
    for (int r = 0; r < 8; ++r) {
        float4 v = acc[r];
#define RED(X) { v.X += __shfl_xor(v.X, 4);  v.X += __shfl_xor(v.X, 8); \
                 v.X += __shfl_xor(v.X, 16); v.X += __shfl_xor(v.X, 32); }
        RED(x) RED(y) RED(z) RED(w)
#undef RED
        const int row = rowbase + r;
        if (lane < 4 && row < NN)
            *(float4*)(P + (size_t)row * HF + jq * 4) = v;
    }
}

// -----------------------------------------------------------------------------
// agg1: A1[n] = sum_{e into n} P[src[e]]. 16 lanes per node: 4 edge-subgroups
// (es) x 4 float4-lanes (q). Butterfly xor 4,8 merges edge groups.
// -----------------------------------------------------------------------------
__global__ __launch_bounds__(256) void agg1_kernel(const float* __restrict__ P,
                                                   const int* __restrict__ cnt,
                                                   const int* __restrict__ ell,
                                                   float* __restrict__ A1) {
    int g = blockIdx.x * 256 + threadIdx.x;
    int node = g >> 4;
    if (node >= NN) return;
    const int l = g & 15, es = l >> 2, q = l & 3;
    int c = cnt[node]; if (c > ELLW) c = ELLW;
    const int* ep = ell + node * ELLW;

    float4 v = {0,0,0,0};
    for (int i = es; i < c; i += 4) {
        int s = ep[i];
        float4 p = *(const float4*)(P + (size_t)s * HF + q * 4);
        v.x += p.x; v.y += p.y; v.z += p.z; v.w += p.w;
    }
#define BFLY2(VAL) { VAL += __shfl_xor(VAL, 4); VAL += __shfl_xor(VAL, 8); }
    BFLY2(v.x) BFLY2(v.y) BFLY2(v.z) BFLY2(v.w)
#undef BFLY2
    if (es == 0)
        *(float4*)(A1 + (size_t)node * HF + q * 4) = v;
}

// -----------------------------------------------------------------------------
// agg2 + output GEMM fused: A2[n] = sum relu(A1[src]+b1) (16 lanes/node),
// then out[n] = A2 @ W2 + b2 via per-q partials + xor 1,2 butterfly.
// -----------------------------------------------------------------------------
__global__ __launch_bounds__(256) void agg2out_kernel(const float* __restrict__ A1,
                                                      const float* __restrict__ b1,
                                                      const int* __restrict__ cnt,
                                                      const int* __restrict__ ell,
                                                      const float* __restrict__ W2,
                                                      const float* __restrict__ b2,
                                                      float* __restrict__ out) {
    __shared__ float W2s[HF * OF];
    __shared__ float b2s[OF];
    const int t = threadIdx.x;
    for (int i = t; i < HF * OF; i += 256) W2s[i] = W2[i];
    if (t < OF) b2s[t] = b2[t];
    __syncthreads();

    int g = blockIdx.x * 256 + t;
    int node = g >> 4;
    if (node >= NN) return;
    const int l = g & 15, es = l >> 2, q = l & 3;

    const float4 bb = *(const float4*)(b1 + q * 4);
    int c = cnt[node]; if (c > ELLW) c = ELLW;
    const int* ep = ell + node * ELLW;

    float4 v = {0,0,0,0};
    for (int i = es; i < c; i += 4) {
        int s = ep[i];
        float4 h = *(const float4*)(A1 + (size_t)s * HF + q * 4);
        h.x = fmaxf(h.x + bb.x, 0.0f);
        h.y = fmaxf(h.y + bb.y, 0.0f);
        h.z = fmaxf(h.z + bb.z, 0.0f);
        h.w = fmaxf(h.w + bb.w, 0.0f);
        v.x += h.x; v.y += h.y; v.z += h.z; v.w += h.w;
    }
#define BFLY2(VAL) { VAL += __shfl_xor(VAL, 4); VAL += __shfl_xor(VAL, 8); }
    BFLY2(v.x) BFLY2(v.y) BFLY2(v.z) BFLY2(v.w)
#undef BFLY2

    const float* w0 = W2s + (q * 4 + 0) * OF;
    const float* w1 = W2s + (q * 4 + 1) * OF;
    const float* w2 = W2s + (q * 4 + 2) * OF;
    const float* w3 = W2s + (q * 4 + 3) * OF;
    float o[OF];
#pragma unroll
    for (int cc = 0; cc < OF; ++cc)
        o[cc] = v.x * w0[cc] + v.y * w1[cc] + v.z * w2[cc] + v.w * w3[cc];
#pragma unroll
    for (int cc = 0; cc < OF; ++cc) {
        o[cc] += __shfl_xor(o[cc], 1);
        o[cc] += __shfl_xor(o[cc], 2);
    }
    if (es == 0) {
        float* op = out + (size_t)node * OF;
        for (int cc = q; cc < OF; cc += 4) op[cc] = o[cc] + b2s[cc];
    }
}

extern "C" void kernel_launch(void* const* d_in, const int* in_sizes, int n_in,
                              void* d_out, int out_size, void* d_ws, size_t ws_size,
                              hipStream_t stream) {
    const float* F   = (const float*)d_in[0];
    const float* W1  = (const float*)d_in[1];
    const float* b1  = (const float*)d_in[2];
    const float* W2  = (const float*)d_in[3];
    const float* b2  = (const float*)d_in[4];
    const int*   src = (const int*)d_in[5];
    const int*   dst = (const int*)d_in[6];
    float* out = (float*)d_out;

    char* ws = (char*)d_ws;
    int*   cnt = (int*)(ws);                       // 200,000 B
    int*   ell = (int*)(ws + 200192);              // 8,000,000 B
    float* P   = (float*)(ws + 8200192);           // 3,200,000 B
    float* A1  = (float*)(ws + 11400192);          // 3,200,000 B

    (void)hipMemsetAsync(cnt, 0, NN * sizeof(int), stream);
    scatter_kernel<<<(NE + 255) / 256, 256, 0, stream>>>(src, dst, cnt, ell);
    gemm1_kernel<<<(NN + 31) / 32, 256, 0, stream>>>(F, W1, P);
    agg1_kernel<<<(NN * 16 + 255) / 256, 256, 0, stream>>>(P, cnt, ell, A1);
    agg2out_kernel<<<(NN * 16 + 255) / 256, 256, 0, stream>>>(A1, b1, cnt, ell, W2, b2, out);
}